// Round 5
// baseline (263.059 us; speedup 1.0000x reference)
//
#include <hip/hip_runtime.h>

// Problem constants (from reference): B=8, E=512, L=4096, D=256, all fp32.
#define B_N 8
#define E_N 512
#define L_N 4096
#define D_N 256

#define SPLITK 8
#define KC_LEN (L_N / SPLITK)   // 512
#define BK 64
#define KC_ITERS (KC_LEN / BK)  // 8

#define ET 128                  // E tile
#define DT 128                  // D tile
#define NTHREADS 512

#define SLICE_ELEMS (B_N * E_N * D_N)           // 1M floats = 4 MB per split slice

typedef __attribute__((ext_vector_type(8))) short short8;   // 8 bf16 (MFMA A/B frag)
typedef __attribute__((ext_vector_type(4))) float f32x4;    // MFMA acc / global float4
typedef __attribute__((ext_vector_type(2))) unsigned int uint2v; // 2x packed bf16 pair

// Packed fp32x2 -> bf16x2 (RNE) in ONE VALU op (R4: VALUBusy 14% -> 4.4%).
__device__ __forceinline__ unsigned cvt_pk_bf16(float lo, float hi) {
    unsigned r;
    asm("v_cvt_pk_bf16_f32 %0, %1, %2" : "=v"(r) : "v"(lo), "v"(hi));
    return r;
}

// LDS tile: [row][64 k] bf16, 128 B per row, NO pad. 16B-chunk XOR swizzle
// (verified R2: SQ_LDS_BANK_CONFLICT 5.2M -> 0). k multiple of 4 at call sites.
__device__ __forceinline__ int swz(int row, int k) {
    return row * 64 + ((((k >> 3) ^ (row & 7)) << 3) | (k & 7));
}

// ---------------- Stage 1: split-K partial GEMM, NO atomics ----------------
// launch_bounds (512, 8): force VGPR<=64 (R3's allocator already landed at 64
// with a single staging set -> no spill expected) so FOUR independent blocks
// fit per CU (LDS 4x32KB=128<160, 32 waves). R3's 2 lockstep blocks/CU left
// the CU empty at every drain point (Occupancy 31%); 4 independent barrier
// groups overlap phases across blocks. Distance-2 reg pipeline is REVERTED:
// it spilled (R4: WRITE_SIZE 33->104 MB at VGPR=64).
__global__ __launch_bounds__(NTHREADS, 8)
void mp_gemm(const float* __restrict__ doc,   // [B, L, D]
             const float* __restrict__ map,   // [B, E, L]
             float* __restrict__ ws)          // [SPLITK, B, E, D] partials
{
    // SINGLE-buffered swizzled tiles: 32 KiB total.
    __shared__ unsigned short As[ET * 64];   // As[m][k] : map tile, K-contig
    __shared__ unsigned short Bs[DT * 64];   // Bs[n][k] : doc tile transposed

    // XCD-chunked swizzle: each XCD owns 8 complete (b,kc) groups whose 8
    // tiles share doc/map panels in that XCD's L2.
    const int p    = (int)blockIdx.x;            // 0..511
    const int w    = ((p & 7) << 6) | (p >> 3);
    const int tile = w & 7;        // et*2 + dt
    const int grp  = w >> 3;       // 0..63
    const int b    = grp & 7;
    const int kc   = grp >> 3;     // 0..7

    const int e0  = (tile >> 1) * ET;   // 4 E tiles
    const int d0  = (tile & 1) * DT;    // 2 D tiles
    const int kc0 = kc * KC_LEN;

    const float* docB = doc + (size_t)b * L_N * D_N;
    const float* mapB = map + (size_t)b * E_N * L_N;
    float* wsB = ws + (size_t)kc * SLICE_ELEMS + (size_t)b * E_N * D_N;

    const int tid  = threadIdx.x;
    const int lane = tid & 63;
    const int wave = tid >> 6;     // 0..7

    // ---- staging assignments ----
    const int aRow0 = tid >> 4;    // 0..31 (rows +32r), 16 lanes x 16B contiguous
    const int aCol4 = tid & 15;
    const int kb = tid & 15;       // k block: varies across lanes (LDS chunk spread)
    const int nb = tid >> 4;       // n block (0..31)

    f32x4 ar[4], br[4];            // single distance-1 staging set (32 VGPRs)

    #define LOAD_SET(K0)                                                                   \
        do {                                                                               \
            _Pragma("unroll")                                                              \
            for (int r = 0; r < 4; ++r)                                                    \
                ar[r] = *(const f32x4*)(mapB + (size_t)(e0 + aRow0 + r * 32) * L_N +       \
                                        (K0) + aCol4 * 4);                                 \
            _Pragma("unroll")                                                              \
            for (int i = 0; i < 4; ++i)                                                    \
                br[i] = *(const f32x4*)(docB + (size_t)((K0) + kb * 4 + i) * D_N +         \
                                        d0 + nb * 4);                                      \
        } while (0)

    // ---- compute setup: 8 waves in 2(m) x 4(n) grid; each wave 64x32 output ----
    const int wm = wave >> 2;      // 0..1 : 64-row block
    const int wn = wave & 3;       // 0..3 : 32-col block
    const int fm = lane & 15;
    const int q  = lane >> 4;

    f32x4 acc[4][2] = {};

    LOAD_SET(kc0);                 // prologue: tile-0 loads in flight

    for (int it = 0; it < KC_ITERS; ++it) {
        // Convert + stage to LDS. Compiler inserts the counted vmcnt wait for
        // ar/br right here (this is the only consumer).
        #pragma unroll
        for (int r = 0; r < 4; ++r) {
            uint2v wv;
            wv[0] = cvt_pk_bf16(ar[r][0], ar[r][1]);
            wv[1] = cvt_pk_bf16(ar[r][2], ar[r][3]);
            *(uint2v*)&As[swz(aRow0 + r * 32, aCol4 * 4)] = wv;
        }
        #pragma unroll
        for (int j = 0; j < 4; ++j) {
            uint2v wv;
            wv[0] = cvt_pk_bf16(br[0][j], br[1][j]);
            wv[1] = cvt_pk_bf16(br[2][j], br[3][j]);
            *(uint2v*)&Bs[swz(nb * 4 + j, kb * 4)] = wv;
        }

        // Reissue the (now-consumed) set for it+1: flight time = barrier +
        // frag-reads + MFMA + barrier + next-iter convert start (~1k cy).
        if (it + 1 < KC_ITERS) LOAD_SET(kc0 + (it + 1) * BK);
        __builtin_amdgcn_sched_barrier(0);

        // Barrier 1: writes visible before reads. LDS-only wait -- globals
        // stay in flight across it.
        asm volatile("s_waitcnt lgkmcnt(0)" ::: "memory");
        __builtin_amdgcn_s_barrier();
        __builtin_amdgcn_sched_barrier(0);

        // Frag reads + MFMA on the staged 128x128x64 tile (2 K-steps of 32).
        // setprio: with 4 phase-desynced blocks/CU, favor the MFMA-issuing wave.
        __builtin_amdgcn_s_setprio(1);
        #pragma unroll
        for (int kk = 0; kk < 2; ++kk) {
            short8 af[4], bf[2];
            #pragma unroll
            for (int mi = 0; mi < 4; ++mi) {
                const int m = wm * 64 + mi * 16 + fm;
                af[mi] = *(const short8*)&As[swz(m, kk * 32 + q * 8)];
            }
            #pragma unroll
            for (int ni = 0; ni < 2; ++ni) {
                const int n = wn * 32 + ni * 16 + fm;
                bf[ni] = *(const short8*)&Bs[swz(n, kk * 32 + q * 8)];
            }
            #pragma unroll
            for (int mi = 0; mi < 4; ++mi)
                #pragma unroll
                for (int ni = 0; ni < 2; ++ni)
                    acc[mi][ni] = __builtin_amdgcn_mfma_f32_16x16x32_bf16(
                        af[mi], bf[ni], acc[mi][ni], 0, 0, 0);
        }
        __builtin_amdgcn_s_setprio(0);

        // Barrier 2 (single-buffer): this iter's reads done in all waves
        // before anyone overwrites the buffer next iter.
        __builtin_amdgcn_s_barrier();
    }
    #undef LOAD_SET

    // ---- epilogue: plain stores of the partial tile to this block's private
    // workspace slice. C/D layout: col = lane&15, row = (lane>>4)*4 + i.
    #pragma unroll
    for (int mi = 0; mi < 4; ++mi) {
        const int rLoc = wm * 64 + mi * 16 + q * 4;
        #pragma unroll
        for (int ni = 0; ni < 2; ++ni) {
            const int c = d0 + wn * 32 + ni * 16 + fm;
            #pragma unroll
            for (int i = 0; i < 4; ++i) {
                const int rr = rLoc + i;
                wsB[(size_t)(e0 + rr) * D_N + c] = acc[mi][ni][i];
            }
        }
    }
}

// ---------------- Stage 2: reduce slices + scale by 1/len ----------------
__global__ __launch_bounds__(256)
void mp_reduce(const float* __restrict__ ws,    // [SPLITK, B*E*D]
               const float* __restrict__ lens,  // [B, E]
               float* __restrict__ out)         // [B*E*D]
{
    const int t = (int)blockIdx.x * 256 + (int)threadIdx.x;  // float4 index
    const size_t off = (size_t)t * 4;
    const int be = t >> 6;            // D/4 = 64 float4 per (b,e) row

    f32x4 s = {};
    #pragma unroll
    for (int k = 0; k < SPLITK; ++k) {
        const f32x4 v = *(const f32x4*)(ws + (size_t)k * SLICE_ELEMS + off);
        s += v;
    }
    const float il = 1.0f / lens[be];
    s *= il;
    *(f32x4*)(out + off) = s;
}

extern "C" void kernel_launch(void* const* d_in, const int* in_sizes, int n_in,
                              void* d_out, int out_size, void* d_ws, size_t ws_size,
                              hipStream_t stream) {
    const float* doc  = (const float*)d_in[0];  // doc_state [B,L,D]
    const float* map  = (const float*)d_in[1];  // entity_mapping [B,E,L]
    const float* lens = (const float*)d_in[2];  // entity_lens [B,E]
    float* out = (float*)d_out;                 // [B,E,D] fp32
    float* ws  = (float*)d_ws;                  // needs 32 MB (SPLITK slices)

    // No memset needed: stage 1 fully writes every ws element, stage 2 fully
    // overwrites out.
    dim3 grid1(SPLITK * 8 * B_N);   // 512 blocks: 8 tiles x 8 b x 8 kc
    mp_gemm<<<grid1, NTHREADS, 0, stream>>>(doc, map, ws);

    dim3 grid2(SLICE_ELEMS / 4 / 256);  // 1024 blocks
    mp_reduce<<<grid2, 256, 0, stream>>>(ws, lens, out);
}

// Round 6
// 140.599 us; speedup vs baseline: 1.8710x; 1.8710x over previous
//
#include <hip/hip_runtime.h>

// Problem constants (from reference): B=8, E=512, L=4096, D=256, all fp32.
#define B_N 8
#define E_N 512
#define L_N 4096
#define D_N 256

#define SPLITK 8
#define KC_LEN (L_N / SPLITK)   // 512
#define BK 64
#define KC_ITERS (KC_LEN / BK)  // 8

#define ET 128                  // E tile
#define DT 128                  // D tile
#define NTHREADS 512

#define SLICE_ELEMS (B_N * E_N * D_N)           // 1M floats = 4 MB per split slice

typedef __attribute__((ext_vector_type(8))) short short8;   // 8 bf16 (MFMA A/B frag)
typedef __attribute__((ext_vector_type(4))) float f32x4;    // MFMA acc / global float4
typedef __attribute__((ext_vector_type(2))) unsigned int uint2v; // 2x packed bf16 pair

// Packed fp32x2 -> bf16x2 (RNE) in ONE VALU op (R4: VALUBusy 14% -> 4.4%).
__device__ __forceinline__ unsigned cvt_pk_bf16(float lo, float hi) {
    unsigned r;
    asm("v_cvt_pk_bf16_f32 %0, %1, %2" : "=v"(r) : "v"(lo), "v"(hi));
    return r;
}

// LDS tile: [row][64 k] bf16, 128 B per row, NO pad. 16B-chunk XOR swizzle
// (verified R2: SQ_LDS_BANK_CONFLICT 5.2M -> 0). k multiple of 4 at call sites.
__device__ __forceinline__ int swz(int row, int k) {
    return row * 64 + ((((k >> 3) ^ (row & 7)) << 3) | (k & 7));
}

// ---------------- Stage 1: split-K partial GEMM, NO atomics ----------------
// launch_bounds (512, 4): VGPR cap 128; allocator lands at 64 with the single
// distance-1 staging set (R3-verified, no spill). Occupancy limiter is then
// LDS: single-buffered 32 KB tiles -> FOUR independent blocks/CU (LDS 128/160,
// 32 waves, VGPR 64*8<=512 per SIMD). R3's 2 lockstep blocks left the CU
// empty at every barrier drain (Occupancy 31%); 4 desynced barrier groups
// fill those bubbles.
// FAILED twice, do not repeat: (512,8) VGPR crush -> spill (R5, WRITE 285MB);
// distance-2 reg pipeline at 128-cap -> spill (R4, WRITE 104MB).
__global__ __launch_bounds__(NTHREADS, 4)
void mp_gemm(const float* __restrict__ doc,   // [B, L, D]
             const float* __restrict__ map,   // [B, E, L]
             float* __restrict__ ws)          // [SPLITK, B, E, D] partials
{
    // SINGLE-buffered swizzled tiles: 32 KiB total.
    __shared__ unsigned short As[ET * 64];   // As[m][k] : map tile, K-contig
    __shared__ unsigned short Bs[DT * 64];   // Bs[n][k] : doc tile transposed

    // XCD-chunked swizzle: each XCD owns 8 complete (b,kc) groups whose 8
    // tiles share doc/map panels in that XCD's L2.
    const int p    = (int)blockIdx.x;            // 0..511
    const int w    = ((p & 7) << 6) | (p >> 3);
    const int tile = w & 7;        // et*2 + dt
    const int grp  = w >> 3;       // 0..63
    const int b    = grp & 7;
    const int kc   = grp >> 3;     // 0..7

    const int e0  = (tile >> 1) * ET;   // 4 E tiles
    const int d0  = (tile & 1) * DT;    // 2 D tiles
    const int kc0 = kc * KC_LEN;

    const float* docB = doc + (size_t)b * L_N * D_N;
    const float* mapB = map + (size_t)b * E_N * L_N;
    float* wsB = ws + (size_t)kc * SLICE_ELEMS + (size_t)b * E_N * D_N;

    const int tid  = threadIdx.x;
    const int lane = tid & 63;
    const int wave = tid >> 6;     // 0..7

    // ---- staging assignments ----
    const int aRow0 = tid >> 4;    // 0..31 (rows +32r), 16 lanes x 16B contiguous
    const int aCol4 = tid & 15;
    const int kb = tid & 15;       // k block: varies across lanes (LDS chunk spread)
    const int nb = tid >> 4;       // n block (0..31)

    f32x4 ar[4], br[4];            // single distance-1 staging set (32 VGPRs)

    #define LOAD_SET(K0)                                                                   \
        do {                                                                               \
            _Pragma("unroll")                                                              \
            for (int r = 0; r < 4; ++r)                                                    \
                ar[r] = *(const f32x4*)(mapB + (size_t)(e0 + aRow0 + r * 32) * L_N +       \
                                        (K0) + aCol4 * 4);                                 \
            _Pragma("unroll")                                                              \
            for (int i = 0; i < 4; ++i)                                                    \
                br[i] = *(const f32x4*)(docB + (size_t)((K0) + kb * 4 + i) * D_N +         \
                                        d0 + nb * 4);                                      \
        } while (0)

    // ---- compute setup: 8 waves in 2(m) x 4(n) grid; each wave 64x32 output ----
    const int wm = wave >> 2;      // 0..1 : 64-row block
    const int wn = wave & 3;       // 0..3 : 32-col block
    const int fm = lane & 15;
    const int q  = lane >> 4;

    f32x4 acc[4][2] = {};

    LOAD_SET(kc0);                 // prologue: tile-0 loads in flight

    for (int it = 0; it < KC_ITERS; ++it) {
        // Convert + stage to LDS. Compiler inserts the counted vmcnt wait for
        // ar/br right here (this is the only consumer).
        #pragma unroll
        for (int r = 0; r < 4; ++r) {
            uint2v wv;
            wv[0] = cvt_pk_bf16(ar[r][0], ar[r][1]);
            wv[1] = cvt_pk_bf16(ar[r][2], ar[r][3]);
            *(uint2v*)&As[swz(aRow0 + r * 32, aCol4 * 4)] = wv;
        }
        #pragma unroll
        for (int j = 0; j < 4; ++j) {
            uint2v wv;
            wv[0] = cvt_pk_bf16(br[0][j], br[1][j]);
            wv[1] = cvt_pk_bf16(br[2][j], br[3][j]);
            *(uint2v*)&Bs[swz(nb * 4 + j, kb * 4)] = wv;
        }

        // Reissue the (now-consumed) set for it+1: flight time = barrier +
        // frag-reads + MFMA + barrier + next-iter convert start.
        if (it + 1 < KC_ITERS) LOAD_SET(kc0 + (it + 1) * BK);
        __builtin_amdgcn_sched_barrier(0);

        // Barrier 1: writes visible before reads. LDS-only wait -- globals
        // stay in flight across it.
        asm volatile("s_waitcnt lgkmcnt(0)" ::: "memory");
        __builtin_amdgcn_s_barrier();
        __builtin_amdgcn_sched_barrier(0);

        // Frag reads + MFMA on the staged 128x128x64 tile (2 K-steps of 32).
        // setprio: with 4 phase-desynced blocks/CU, favor the MFMA-issuing wave.
        __builtin_amdgcn_s_setprio(1);
        #pragma unroll
        for (int kk = 0; kk < 2; ++kk) {
            short8 af[4], bf[2];
            #pragma unroll
            for (int mi = 0; mi < 4; ++mi) {
                const int m = wm * 64 + mi * 16 + fm;
                af[mi] = *(const short8*)&As[swz(m, kk * 32 + q * 8)];
            }
            #pragma unroll
            for (int ni = 0; ni < 2; ++ni) {
                const int n = wn * 32 + ni * 16 + fm;
                bf[ni] = *(const short8*)&Bs[swz(n, kk * 32 + q * 8)];
            }
            #pragma unroll
            for (int mi = 0; mi < 4; ++mi)
                #pragma unroll
                for (int ni = 0; ni < 2; ++ni)
                    acc[mi][ni] = __builtin_amdgcn_mfma_f32_16x16x32_bf16(
                        af[mi], bf[ni], acc[mi][ni], 0, 0, 0);
        }
        __builtin_amdgcn_s_setprio(0);

        // Barrier 2 (single-buffer): this iter's reads done in all waves
        // before anyone overwrites the buffer next iter. sched_barrier keeps
        // next-iter ds_writes from hoisting above it (raw s_barrier is
        // convergent but NOT a compiler memory fence).
        __builtin_amdgcn_s_barrier();
        __builtin_amdgcn_sched_barrier(0);
    }
    #undef LOAD_SET

    // ---- epilogue: plain stores of the partial tile to this block's private
    // workspace slice. C/D layout: col = lane&15, row = (lane>>4)*4 + i.
    #pragma unroll
    for (int mi = 0; mi < 4; ++mi) {
        const int rLoc = wm * 64 + mi * 16 + q * 4;
        #pragma unroll
        for (int ni = 0; ni < 2; ++ni) {
            const int c = d0 + wn * 32 + ni * 16 + fm;
            #pragma unroll
            for (int i = 0; i < 4; ++i) {
                const int rr = rLoc + i;
                wsB[(size_t)(e0 + rr) * D_N + c] = acc[mi][ni][i];
            }
        }
    }
}

// ---------------- Stage 2: reduce slices + scale by 1/len ----------------
__global__ __launch_bounds__(256)
void mp_reduce(const float* __restrict__ ws,    // [SPLITK, B*E*D]
               const float* __restrict__ lens,  // [B, E]
               float* __restrict__ out)         // [B*E*D]
{
    const int t = (int)blockIdx.x * 256 + (int)threadIdx.x;  // float4 index
    const size_t off = (size_t)t * 4;
    const int be = t >> 6;            // D/4 = 64 float4 per (b,e) row

    f32x4 s = {};
    #pragma unroll
    for (int k = 0; k < SPLITK; ++k) {
        const f32x4 v = *(const f32x4*)(ws + (size_t)k * SLICE_ELEMS + off);
        s += v;
    }
    const float il = 1.0f / lens[be];
    s *= il;
    *(f32x4*)(out + off) = s;
}

extern "C" void kernel_launch(void* const* d_in, const int* in_sizes, int n_in,
                              void* d_out, int out_size, void* d_ws, size_t ws_size,
                              hipStream_t stream) {
    const float* doc  = (const float*)d_in[0];  // doc_state [B,L,D]
    const float* map  = (const float*)d_in[1];  // entity_mapping [B,E,L]
    const float* lens = (const float*)d_in[2];  // entity_lens [B,E]
    float* out = (float*)d_out;                 // [B,E,D] fp32
    float* ws  = (float*)d_ws;                  // needs 32 MB (SPLITK slices)

    // No memset needed: stage 1 fully writes every ws element, stage 2 fully
    // overwrites out.
    dim3 grid1(SPLITK * 8 * B_N);   // 512 blocks: 8 tiles x 8 b x 8 kc
    mp_gemm<<<grid1, NTHREADS, 0, stream>>>(doc, map, ws);

    dim3 grid2(SLICE_ELEMS / 4 / 256);  // 1024 blocks
    mp_reduce<<<grid2, 256, 0, stream>>>(ws, lens, out);
}